// Round 1
// baseline (444.095 us; speedup 1.0000x reference)
//
#include <hip/hip_runtime.h>
#include <math.h>

#define N_NODES 4096
#define F_DIM   128
#define E_EDGES 131072
#define NHEADS  8
#define HD      16
#define C_OUT   64

// ---------------- graph prep ----------------
__global__ void deg_count(const int* __restrict__ col, int* __restrict__ deg) {
  int e = blockIdx.x * blockDim.x + threadIdx.x;
  if (e < E_EDGES) atomicAdd(&deg[col[e]], 1);
}

__global__ void dinv_kernel(const int* __restrict__ deg, float* __restrict__ dinv) {
  int i = blockIdx.x * blockDim.x + threadIdx.x;
  if (i < N_NODES) dinv[i] = rsqrtf((float)(deg[i] + 1));  // +1 self-loop
}

// exclusive prefix sum of deg[4096] -> offs[4097]; single block, 1024 thr x 4
__global__ void scan_kernel(const int* __restrict__ deg, int* __restrict__ offs) {
  __shared__ int part[1024];
  int t = threadIdx.x;
  int v0 = deg[t*4+0], v1 = deg[t*4+1], v2 = deg[t*4+2], v3 = deg[t*4+3];
  int s = v0 + v1 + v2 + v3;
  part[t] = s;
  __syncthreads();
  for (int off = 1; off < 1024; off <<= 1) {
    int x = (t >= off) ? part[t - off] : 0;
    __syncthreads();
    part[t] += x;
    __syncthreads();
  }
  int excl = part[t] - s;
  offs[t*4+0] = excl; excl += v0;
  offs[t*4+1] = excl; excl += v1;
  offs[t*4+2] = excl; excl += v2;
  offs[t*4+3] = excl; excl += v3;
  if (t == 1023) offs[4096] = excl;   // == E_EDGES
}

__global__ void fill_csr(const int* __restrict__ row, const int* __restrict__ col,
                         const int* __restrict__ offs, int* __restrict__ cursor,
                         int* __restrict__ src) {
  int e = blockIdx.x * blockDim.x + threadIdx.x;
  if (e < E_EDGES) {
    int c = col[e];
    int p = atomicAdd(&cursor[c], 1);
    src[offs[c] + p] = row[e];
  }
}

// out[c][f] = relu( (t[c][f]*dinv[c] + sum_r t[r][f]*dinv[r]) * dinv[c] + b[f] )
__global__ void gcn_agg(const float* __restrict__ t, const float* __restrict__ dinv,
                        const int* __restrict__ offs, const int* __restrict__ src,
                        const float* __restrict__ bias, float* __restrict__ out) {
  int c = blockIdx.x;
  int f = threadIdx.x;
  float dc = dinv[c];
  float acc = t[c * F_DIM + f] * dc;     // self-loop (x dc again below)
  int e = offs[c], end = offs[c + 1];
  for (; e + 4 <= end; e += 4) {
    int r0 = src[e], r1 = src[e+1], r2 = src[e+2], r3 = src[e+3];
    float w0 = dinv[r0], w1 = dinv[r1], w2 = dinv[r2], w3 = dinv[r3];
    float v0 = t[r0*F_DIM + f], v1 = t[r1*F_DIM + f];
    float v2 = t[r2*F_DIM + f], v3 = t[r3*F_DIM + f];
    acc += v0*w0 + v1*w1 + v2*w2 + v3*w3;
  }
  for (; e < end; ++e) { int r = src[e]; acc += t[r*F_DIM + f] * dinv[r]; }
  float res = acc * dc + bias[f];
  out[c * F_DIM + f] = fmaxf(res, 0.f);
}

// ---------------- GEMM: C[M x ldc], tile TM=16 rows x NC cols, 4x4/thread ----
// NT=false: B is [K x NC] row-major (cols == NC exactly)
// NT=true : B is [ncols_total x K] row-major (use rows jg0..jg0+NC-1), NC==128
template<int NC, bool NT, bool BIAS, bool RELU, bool EXTRA>
__global__ __launch_bounds__(NC) void gemm_k(const float* __restrict__ A,
                                             const float* __restrict__ B,
                                             const float* __restrict__ bias,
                                             const float* __restrict__ extra,
                                             float* __restrict__ C, int ldc) {
  constexpr int TM = 16;
  constexpr int K  = 128;
  __shared__ float Ast[K * TM];   // [k][i]
  __shared__ float Bs[K * NC];    // [k][j]
  const int tid  = threadIdx.x;
  const int row0 = blockIdx.x * TM;
  const int jg0  = blockIdx.y * NC;

  // stage A transposed (TM x K -> [k][i])
  for (int fi = tid; fi < TM * K / 4; fi += NC) {
    int i  = fi >> 5;        // K/4 = 32 float4 per row
    int c4 = fi & 31;
    const float4 g = *(const float4*)&A[(row0 + i) * K + c4 * 4];
    Ast[(c4*4+0)*TM + i] = g.x;
    Ast[(c4*4+1)*TM + i] = g.y;
    Ast[(c4*4+2)*TM + i] = g.z;
    Ast[(c4*4+3)*TM + i] = g.w;
  }
  if constexpr (NT) {
    // thread tid owns Bt row (jg0+tid); transpose into Bs[k][j]
    int j = tid;
    for (int i4 = 0; i4 < K / 4; ++i4) {
      const float4 g = *(const float4*)&B[(jg0 + j) * K + i4 * 4];
      Bs[(i4*4+0)*NC + j] = g.x;
      Bs[(i4*4+1)*NC + j] = g.y;
      Bs[(i4*4+2)*NC + j] = g.z;
      Bs[(i4*4+3)*NC + j] = g.w;
    }
  } else {
    for (int fi = tid; fi < K * NC / 4; fi += NC) {
      int k  = fi / (NC / 4);
      int c4 = fi % (NC / 4);
      *(float4*)&Bs[k * NC + c4 * 4] = *(const float4*)&B[k * NC + c4 * 4];
    }
  }
  __syncthreads();

  constexpr int CT = NC / 4;        // col-thread count
  const int r0 = (tid / CT) * 4;    // 0,4,8,12
  const int c0 = (tid % CT) * 4;
  float acc[4][4] = {{0.f}};
  #pragma unroll 4
  for (int k = 0; k < K; ++k) {
    const float4 av = *(const float4*)&Ast[k * TM + r0];
    const float4 bv = *(const float4*)&Bs[k * NC + c0];
    float ar[4] = {av.x, av.y, av.z, av.w};
    float br[4] = {bv.x, bv.y, bv.z, bv.w};
    #pragma unroll
    for (int r = 0; r < 4; ++r)
      #pragma unroll
      for (int c = 0; c < 4; ++c) acc[r][c] = fmaf(ar[r], br[c], acc[r][c]);
  }
  #pragma unroll
  for (int r = 0; r < 4; ++r) {
    int gr = row0 + r0 + r;
    #pragma unroll
    for (int c = 0; c < 4; ++c) {
      int gc = jg0 + c0 + c;
      float v = acc[r][c];
      if constexpr (BIAS)  v += bias[gc];
      if constexpr (EXTRA) v += extra[gr * ldc + gc];
      if constexpr (RELU)  v = fmaxf(v, 0.f);
      C[gr * ldc + gc] = v;
    }
  }
}

// ---------------- flash attention (8 heads, d=16, N=4096) ----------------
// qkv: [N,384] (q|k|v). o: [N,128]. Block: 64 rows x 4 key-subsets, 256 thr.
__global__ __launch_bounds__(256) void attn_kernel(const float* __restrict__ qkv,
                                                   float* __restrict__ o) {
  constexpr int TQ = 64, TK = 512;
  __shared__ float Ks[TK * HD];   // 32 KB
  __shared__ float Vs[TK * HD];   // 32 KB
  const int h    = blockIdx.y;
  const int rl   = threadIdx.x >> 2;
  const int sub  = threadIdx.x & 3;
  const int rowg = blockIdx.x * TQ + rl;

  float q[HD];
  const float* qp = &qkv[rowg * 384 + h * HD];
  #pragma unroll
  for (int d = 0; d < HD; ++d) q[d] = qp[d] * 0.25f;   // fold 1/sqrt(16)

  float m = -INFINITY, l = 0.f;
  float oa[HD];
  #pragma unroll
  for (int d = 0; d < HD; ++d) oa[d] = 0.f;

  for (int kt = 0; kt < N_NODES; kt += TK) {
    __syncthreads();
    for (int fi = threadIdx.x; fi < TK * HD / 4; fi += 256) {
      int r = fi >> 2, q4 = fi & 3;
      ((float4*)Ks)[fi] = *(const float4*)&qkv[(kt + r) * 384 + 128 + h * HD + q4 * 4];
      ((float4*)Vs)[fi] = *(const float4*)&qkv[(kt + r) * 384 + 256 + h * HD + q4 * 4];
    }
    __syncthreads();
    for (int j = sub; j < TK; j += 4) {
      const float* kp = &Ks[j * HD];
      float s = 0.f;
      #pragma unroll
      for (int d = 0; d < HD; ++d) s = fmaf(q[d], kp[d], s);
      const float* vp = &Vs[j * HD];
      if (s <= m) {
        float p = __expf(s - m);
        l += p;
        #pragma unroll
        for (int d = 0; d < HD; ++d) oa[d] = fmaf(p, vp[d], oa[d]);
      } else {
        float cor = __expf(m - s);
        l = fmaf(l, cor, 1.f);
        #pragma unroll
        for (int d = 0; d < HD; ++d) oa[d] = fmaf(oa[d], cor, vp[d]);
        m = s;
      }
    }
  }
  __syncthreads();
  // merge the 4 sub-partials per row via LDS (reuse Ks/Vs)
  Vs[rl*4 + sub]       = m;
  Vs[256 + rl*4 + sub] = l;
  #pragma unroll
  for (int d = 0; d < HD; ++d) Ks[(rl*4 + sub) * HD + d] = oa[d];
  __syncthreads();
  float m0 = Vs[rl*4+0], m1 = Vs[rl*4+1], m2 = Vs[rl*4+2], m3 = Vs[rl*4+3];
  float M  = fmaxf(fmaxf(m0, m1), fmaxf(m2, m3));
  float w0 = __expf(m0 - M), w1 = __expf(m1 - M), w2 = __expf(m2 - M), w3 = __expf(m3 - M);
  float L  = Vs[256+rl*4+0]*w0 + Vs[256+rl*4+1]*w1 + Vs[256+rl*4+2]*w2 + Vs[256+rl*4+3]*w3;
  float invL = 1.f / L;
  const float* kb = &Ks[rl * 4 * HD];
  int d0 = sub * 4;
  float4 r;
  r.x = (kb[0*HD+d0+0]*w0 + kb[1*HD+d0+0]*w1 + kb[2*HD+d0+0]*w2 + kb[3*HD+d0+0]*w3) * invL;
  r.y = (kb[0*HD+d0+1]*w0 + kb[1*HD+d0+1]*w1 + kb[2*HD+d0+1]*w2 + kb[3*HD+d0+1]*w3) * invL;
  r.z = (kb[0*HD+d0+2]*w0 + kb[1*HD+d0+2]*w1 + kb[2*HD+d0+2]*w2 + kb[3*HD+d0+2]*w3) * invL;
  r.w = (kb[0*HD+d0+3]*w0 + kb[1*HD+d0+3]*w1 + kb[2*HD+d0+3]*w2 + kb[3*HD+d0+3]*w3) * invL;
  *(float4*)&o[rowg * F_DIM + h * HD + d0] = r;
}

// ---------------- launcher ----------------
extern "C" void kernel_launch(void* const* d_in, const int* in_sizes, int n_in,
                              void* d_out, int out_size, void* d_ws, size_t ws_size,
                              hipStream_t stream) {
  const float* x   = (const float*)d_in[0];
  const int*   ei  = (const int*)  d_in[1];
  const float* W1  = (const float*)d_in[2];
  const float* b1  = (const float*)d_in[3];
  const float* W2  = (const float*)d_in[4];
  const float* b2  = (const float*)d_in[5];
  const float* W3  = (const float*)d_in[6];
  const float* b3  = (const float*)d_in[7];
  const float* ipw = (const float*)d_in[8];
  const float* ipb = (const float*)d_in[9];
  const float* opw = (const float*)d_in[10];
  const float* opb = (const float*)d_in[11];
  const float* pw  = (const float*)d_in[12];
  const float* pb  = (const float*)d_in[13];
  float* out = (float*)d_out;

  // workspace layout (all 16B aligned)
  int*   deg    = (int*)d_ws;            // 4096
  int*   cursor = deg + 4096;            // 4096
  int*   offs   = cursor + 4096;         // 4100 (4097 used)
  int*   csrc   = offs + 4100;           // 131072
  float* dinv   = (float*)(csrc + E_EDGES);        // 4096
  float* bufA   = dinv + 4096;           // 524288 (t0/t1, then x_gnn)
  float* bufB   = bufA + 524288;         // 524288 (h1/h2, then x_tf)
  float* qkv    = bufB + 524288;         // 1572864
  float* obuf   = qkv + 1572864;         // 524288

  const int* rowp = ei;
  const int* colp = ei + E_EDGES;

  hipMemsetAsync(deg, 0, 8192 * sizeof(int), stream);  // deg + cursor
  deg_count<<<E_EDGES / 256, 256, 0, stream>>>(colp, deg);
  dinv_kernel<<<N_NODES / 256, 256, 0, stream>>>(deg, dinv);
  scan_kernel<<<1, 1024, 0, stream>>>(deg, offs);
  fill_csr<<<E_EDGES / 256, 256, 0, stream>>>(rowp, colp, offs, cursor, csrc);

  // GCN branch
  gemm_k<128, false, false, false, false><<<dim3(256, 1), 128, 0, stream>>>(
      x, W1, nullptr, nullptr, bufA, 128);
  gcn_agg<<<N_NODES, 128, 0, stream>>>(bufA, dinv, offs, csrc, b1, bufB);
  gemm_k<128, false, false, false, false><<<dim3(256, 1), 128, 0, stream>>>(
      bufB, W2, nullptr, nullptr, bufA, 128);
  gcn_agg<<<N_NODES, 128, 0, stream>>>(bufA, dinv, offs, csrc, b2, bufB);
  // x_gnn = h2@W3 + b3 -> bufA (t1 dead)
  gemm_k<64, false, true, false, false><<<dim3(256, 1), 64, 0, stream>>>(
      bufB, W3, b3, nullptr, bufA, C_OUT);

  // transformer branch
  gemm_k<128, true, true, false, false><<<dim3(256, 3), 128, 0, stream>>>(
      x, ipw, ipb, nullptr, qkv, 384);
  attn_kernel<<<dim3(64, NHEADS), 256, 0, stream>>>(qkv, obuf);
  gemm_k<128, true, true, false, false><<<dim3(256, 1), 128, 0, stream>>>(
      obuf, opw, opb, nullptr, bufB, 128);
  // out = relu(x_tf @ proj_w + proj_b + x_gnn)
  gemm_k<64, false, true, true, true><<<dim3(256, 1), 64, 0, stream>>>(
      bufB, pw, pb, bufA, out, C_OUT);
}

// Round 2
// 382.108 us; speedup vs baseline: 1.1622x; 1.1622x over previous
//
#include <hip/hip_runtime.h>
#include <math.h>

#define N_NODES 4096
#define F_DIM   128
#define E_EDGES 131072
#define NHEADS  8
#define HD      16
#define C_OUT   64

// ---------------- graph prep ----------------
__global__ void deg_count(const int* __restrict__ col, int* __restrict__ deg) {
  int e = blockIdx.x * blockDim.x + threadIdx.x;
  if (e < E_EDGES) atomicAdd(&deg[col[e]], 1);
}

__global__ void dinv_kernel(const int* __restrict__ deg, float* __restrict__ dinv) {
  int i = blockIdx.x * blockDim.x + threadIdx.x;
  if (i < N_NODES) dinv[i] = rsqrtf((float)(deg[i] + 1));  // +1 self-loop
}

// exclusive prefix sum of deg[4096] -> offs[4097]; single block, 1024 thr x 4
__global__ void scan_kernel(const int* __restrict__ deg, int* __restrict__ offs) {
  __shared__ int part[1024];
  int t = threadIdx.x;
  int v0 = deg[t*4+0], v1 = deg[t*4+1], v2 = deg[t*4+2], v3 = deg[t*4+3];
  int s = v0 + v1 + v2 + v3;
  part[t] = s;
  __syncthreads();
  for (int off = 1; off < 1024; off <<= 1) {
    int x = (t >= off) ? part[t - off] : 0;
    __syncthreads();
    part[t] += x;
    __syncthreads();
  }
  int excl = part[t] - s;
  offs[t*4+0] = excl; excl += v0;
  offs[t*4+1] = excl; excl += v1;
  offs[t*4+2] = excl; excl += v2;
  offs[t*4+3] = excl; excl += v3;
  if (t == 1023) offs[4096] = excl;   // == E_EDGES
}

__global__ void fill_csr(const int* __restrict__ row, const int* __restrict__ col,
                         const int* __restrict__ offs, int* __restrict__ cursor,
                         int* __restrict__ src) {
  int e = blockIdx.x * blockDim.x + threadIdx.x;
  if (e < E_EDGES) {
    int c = col[e];
    int p = atomicAdd(&cursor[c], 1);
    src[offs[c] + p] = row[e];
  }
}

// out[c][f] = relu( (t[c][f]*dinv[c] + sum_r t[r][f]*dinv[r]) * dinv[c] + b[f] )
__global__ void gcn_agg(const float* __restrict__ t, const float* __restrict__ dinv,
                        const int* __restrict__ offs, const int* __restrict__ src,
                        const float* __restrict__ bias, float* __restrict__ out) {
  int c = blockIdx.x;
  int f = threadIdx.x;
  float dc = dinv[c];
  float acc = t[c * F_DIM + f] * dc;
  int e = offs[c], end = offs[c + 1];
  for (; e + 4 <= end; e += 4) {
    int r0 = src[e], r1 = src[e+1], r2 = src[e+2], r3 = src[e+3];
    float w0 = dinv[r0], w1 = dinv[r1], w2 = dinv[r2], w3 = dinv[r3];
    float v0 = t[r0*F_DIM + f], v1 = t[r1*F_DIM + f];
    float v2 = t[r2*F_DIM + f], v3 = t[r3*F_DIM + f];
    acc += v0*w0 + v1*w1 + v2*w2 + v3*w3;
  }
  for (; e < end; ++e) { int r = src[e]; acc += t[r*F_DIM + f] * dinv[r]; }
  float res = acc * dc + bias[f];
  out[c * F_DIM + f] = fmaxf(res, 0.f);
}

// ---------------- GEMM v2: TM x 64 tile, BK=32, 256 threads ----------------
// NT=false: B is [K x ldb] row-major; NT=true: B is [Ntot x K] row-major.
template<int TM, bool NT, bool BIAS, bool RELU, bool EXTRA>
__global__ __launch_bounds__(256) void gemm2(const float* __restrict__ A,
                                             const float* __restrict__ B,
                                             const float* __restrict__ bias,
                                             const float* __restrict__ extra,
                                             float* __restrict__ C,
                                             int ldb, int ldc) {
  constexpr int K = 128, BK = 32, TN = 64;
  constexpr int RM = TM * TN / 1024;      // rows per thread: 1 (TM=16) or 2 (TM=32)
  constexpr int LDA = 36;                 // padded [k][m] stride
  constexpr int LDB = TN + 4;             // padded [k][n] stride (16B-aligned rows)
  __shared__ float As[BK * LDA];
  __shared__ float Bs[BK * LDB];
  const int tid = threadIdx.x;
  const int tx = tid & 15;                // col group: tx*4
  const int ty = tid >> 4;                // row group: ty*RM
  const int row0 = blockIdx.x * TM;
  const int jg0  = blockIdx.y * TN;

  float acc[RM][4];
  #pragma unroll
  for (int r = 0; r < RM; ++r) { acc[r][0]=0.f; acc[r][1]=0.f; acc[r][2]=0.f; acc[r][3]=0.f; }

  for (int kc = 0; kc < K; kc += BK) {
    __syncthreads();
    // stage A tile (TM x BK) transposed into As[k][m]
    {
      constexpr int NL = TM * BK / 4;     // float4 loads
      for (int idx = tid; idx < NL; idx += 256) {
        int m  = idx >> 3;                // BK/4 = 8
        int k4 = idx & 7;
        const float4 g = *(const float4*)&A[(row0 + m) * K + kc + k4 * 4];
        As[(k4*4+0)*LDA + m] = g.x;
        As[(k4*4+1)*LDA + m] = g.y;
        As[(k4*4+2)*LDA + m] = g.z;
        As[(k4*4+3)*LDA + m] = g.w;
      }
    }
    if constexpr (NT) {
      constexpr int NL = TN * 8;          // TN rows x BK/4
      for (int idx = tid; idx < NL; idx += 256) {
        int n  = idx >> 3;
        int k4 = idx & 7;
        const float4 g = *(const float4*)&B[(jg0 + n) * K + kc + k4 * 4];
        Bs[(k4*4+0)*LDB + n] = g.x;
        Bs[(k4*4+1)*LDB + n] = g.y;
        Bs[(k4*4+2)*LDB + n] = g.z;
        Bs[(k4*4+3)*LDB + n] = g.w;
      }
    } else {
      constexpr int NL = BK * TN / 4;
      for (int idx = tid; idx < NL; idx += 256) {
        int k  = idx >> 4;                // TN/4 = 16
        int n4 = idx & 15;
        *(float4*)&Bs[k * LDB + n4 * 4] =
            *(const float4*)&B[(kc + k) * ldb + jg0 + n4 * 4];
      }
    }
    __syncthreads();
    #pragma unroll
    for (int k = 0; k < BK; ++k) {
      const float4 bv = *(const float4*)&Bs[k * LDB + tx * 4];
      #pragma unroll
      for (int r = 0; r < RM; ++r) {
        const float a = As[k * LDA + ty * RM + r];
        acc[r][0] = fmaf(a, bv.x, acc[r][0]);
        acc[r][1] = fmaf(a, bv.y, acc[r][1]);
        acc[r][2] = fmaf(a, bv.z, acc[r][2]);
        acc[r][3] = fmaf(a, bv.w, acc[r][3]);
      }
    }
  }

  #pragma unroll
  for (int r = 0; r < RM; ++r) {
    const int gr = row0 + ty * RM + r;
    const int gc = jg0 + tx * 4;
    float4 v = make_float4(acc[r][0], acc[r][1], acc[r][2], acc[r][3]);
    if constexpr (BIAS) {
      const float4 bb = *(const float4*)&bias[gc];
      v.x += bb.x; v.y += bb.y; v.z += bb.z; v.w += bb.w;
    }
    if constexpr (EXTRA) {
      const float4 e = *(const float4*)&extra[gr * ldc + gc];
      v.x += e.x; v.y += e.y; v.z += e.z; v.w += e.w;
    }
    if constexpr (RELU) {
      v.x = fmaxf(v.x, 0.f); v.y = fmaxf(v.y, 0.f);
      v.z = fmaxf(v.z, 0.f); v.w = fmaxf(v.w, 0.f);
    }
    *(float4*)&C[gr * ldc + gc] = v;
  }
}

// ---------------- flash attention v2 (8 heads, d=16, N=4096) ----------------
// 8 independent key-chains per thread + branchless block online-softmax.
__global__ __launch_bounds__(256) void attn_kernel(const float* __restrict__ qkv,
                                                   float* __restrict__ o) {
  constexpr int TQ = 64, TK = 512;
  __shared__ float Ks[TK * HD];   // 32 KB
  __shared__ float Vs[TK * HD];   // 32 KB
  const int h    = blockIdx.y;
  const int rl   = threadIdx.x >> 2;
  const int sub  = threadIdx.x & 3;
  const int rowg = blockIdx.x * TQ + rl;

  const float4* qp = (const float4*)&qkv[rowg * 384 + h * HD];
  float4 q0 = qp[0], q1 = qp[1], q2 = qp[2], q3 = qp[3];
  q0.x*=0.25f; q0.y*=0.25f; q0.z*=0.25f; q0.w*=0.25f;
  q1.x*=0.25f; q1.y*=0.25f; q1.z*=0.25f; q1.w*=0.25f;
  q2.x*=0.25f; q2.y*=0.25f; q2.z*=0.25f; q2.w*=0.25f;
  q3.x*=0.25f; q3.y*=0.25f; q3.z*=0.25f; q3.w*=0.25f;

  float m = -INFINITY, l = 0.f;
  float oa[HD];
  #pragma unroll
  for (int d = 0; d < HD; ++d) oa[d] = 0.f;

  for (int kt = 0; kt < N_NODES; kt += TK) {
    __syncthreads();
    for (int fi = threadIdx.x; fi < TK * HD / 4; fi += 256) {
      int r = fi >> 2, c4 = fi & 3;
      ((float4*)Ks)[fi] = *(const float4*)&qkv[(kt + r) * 384 + 128 + h * HD + c4 * 4];
      ((float4*)Vs)[fi] = *(const float4*)&qkv[(kt + r) * 384 + 256 + h * HD + c4 * 4];
    }
    __syncthreads();

    for (int j0 = 0; j0 < TK; j0 += 32) {       // this thread: keys j0+sub+4*i
      float s[8];
      #pragma unroll
      for (int i = 0; i < 8; ++i) {
        const float4* kp = (const float4*)&Ks[(j0 + 4*i + sub) * HD];
        const float4 k0 = kp[0], k1 = kp[1], k2 = kp[2], k3 = kp[3];
        float p0 = fmaf(q0.x,k0.x, fmaf(q0.y,k0.y, fmaf(q0.z,k0.z, q0.w*k0.w)));
        float p1 = fmaf(q1.x,k1.x, fmaf(q1.y,k1.y, fmaf(q1.z,k1.z, q1.w*k1.w)));
        float p2 = fmaf(q2.x,k2.x, fmaf(q2.y,k2.y, fmaf(q2.z,k2.z, q2.w*k2.w)));
        float p3 = fmaf(q3.x,k3.x, fmaf(q3.y,k3.y, fmaf(q3.z,k3.z, q3.w*k3.w)));
        s[i] = (p0 + p1) + (p2 + p3);
      }
      float bm = fmaxf(fmaxf(fmaxf(s[0],s[1]), fmaxf(s[2],s[3])),
                       fmaxf(fmaxf(s[4],s[5]), fmaxf(s[6],s[7])));
      float mnew = fmaxf(m, bm);
      float cor = __expf(m - mnew);
      float p[8];
      #pragma unroll
      for (int i = 0; i < 8; ++i) p[i] = __expf(s[i] - mnew);
      float ps = ((p[0]+p[1]) + (p[2]+p[3])) + ((p[4]+p[5]) + (p[6]+p[7]));
      l = fmaf(l, cor, ps);
      m = mnew;
      #pragma unroll
      for (int d = 0; d < HD; ++d) oa[d] *= cor;
      #pragma unroll
      for (int i = 0; i < 8; ++i) {
        const float4* vp = (const float4*)&Vs[(j0 + 4*i + sub) * HD];
        const float4 v0 = vp[0], v1 = vp[1], v2 = vp[2], v3 = vp[3];
        oa[0]  = fmaf(p[i], v0.x, oa[0]);  oa[1]  = fmaf(p[i], v0.y, oa[1]);
        oa[2]  = fmaf(p[i], v0.z, oa[2]);  oa[3]  = fmaf(p[i], v0.w, oa[3]);
        oa[4]  = fmaf(p[i], v1.x, oa[4]);  oa[5]  = fmaf(p[i], v1.y, oa[5]);
        oa[6]  = fmaf(p[i], v1.z, oa[6]);  oa[7]  = fmaf(p[i], v1.w, oa[7]);
        oa[8]  = fmaf(p[i], v2.x, oa[8]);  oa[9]  = fmaf(p[i], v2.y, oa[9]);
        oa[10] = fmaf(p[i], v2.z, oa[10]); oa[11] = fmaf(p[i], v2.w, oa[11]);
        oa[12] = fmaf(p[i], v3.x, oa[12]); oa[13] = fmaf(p[i], v3.y, oa[13]);
        oa[14] = fmaf(p[i], v3.z, oa[14]); oa[15] = fmaf(p[i], v3.w, oa[15]);
      }
    }
  }
  __syncthreads();
  // merge the 4 sub-partials per row via LDS (reuse Ks/Vs)
  Vs[rl*4 + sub]       = m;
  Vs[256 + rl*4 + sub] = l;
  #pragma unroll
  for (int d = 0; d < HD; ++d) Ks[(rl*4 + sub) * HD + d] = oa[d];
  __syncthreads();
  float m0 = Vs[rl*4+0], m1 = Vs[rl*4+1], m2 = Vs[rl*4+2], m3 = Vs[rl*4+3];
  float M  = fmaxf(fmaxf(m0, m1), fmaxf(m2, m3));
  float w0 = __expf(m0 - M), w1 = __expf(m1 - M), w2 = __expf(m2 - M), w3 = __expf(m3 - M);
  float L  = Vs[256+rl*4+0]*w0 + Vs[256+rl*4+1]*w1 + Vs[256+rl*4+2]*w2 + Vs[256+rl*4+3]*w3;
  float invL = 1.f / L;
  const float* kb = &Ks[rl * 4 * HD];
  int d0 = sub * 4;
  float4 r;
  r.x = (kb[0*HD+d0+0]*w0 + kb[1*HD+d0+0]*w1 + kb[2*HD+d0+0]*w2 + kb[3*HD+d0+0]*w3) * invL;
  r.y = (kb[0*HD+d0+1]*w0 + kb[1*HD+d0+1]*w1 + kb[2*HD+d0+1]*w2 + kb[3*HD+d0+1]*w3) * invL;
  r.z = (kb[0*HD+d0+2]*w0 + kb[1*HD+d0+2]*w1 + kb[2*HD+d0+2]*w2 + kb[3*HD+d0+2]*w3) * invL;
  r.w = (kb[0*HD+d0+3]*w0 + kb[1*HD+d0+3]*w1 + kb[2*HD+d0+3]*w2 + kb[3*HD+d0+3]*w3) * invL;
  *(float4*)&o[rowg * F_DIM + h * HD + d0] = r;
}

// ---------------- launcher ----------------
extern "C" void kernel_launch(void* const* d_in, const int* in_sizes, int n_in,
                              void* d_out, int out_size, void* d_ws, size_t ws_size,
                              hipStream_t stream) {
  const float* x   = (const float*)d_in[0];
  const int*   ei  = (const int*)  d_in[1];
  const float* W1  = (const float*)d_in[2];
  const float* b1  = (const float*)d_in[3];
  const float* W2  = (const float*)d_in[4];
  const float* b2  = (const float*)d_in[5];
  const float* W3  = (const float*)d_in[6];
  const float* b3  = (const float*)d_in[7];
  const float* ipw = (const float*)d_in[8];
  const float* ipb = (const float*)d_in[9];
  const float* opw = (const float*)d_in[10];
  const float* opb = (const float*)d_in[11];
  const float* pw  = (const float*)d_in[12];
  const float* pb  = (const float*)d_in[13];
  float* out = (float*)d_out;

  int*   deg    = (int*)d_ws;            // 4096
  int*   cursor = deg + 4096;            // 4096
  int*   offs   = cursor + 4096;         // 4100 (4097 used)
  int*   csrc   = offs + 4100;           // 131072
  float* dinv   = (float*)(csrc + E_EDGES);        // 4096
  float* bufA   = dinv + 4096;           // 524288
  float* bufB   = bufA + 524288;         // 524288
  float* qkv    = bufB + 524288;         // 1572864
  float* obuf   = qkv + 1572864;         // 524288

  const int* rowp = ei;
  const int* colp = ei + E_EDGES;

  hipMemsetAsync(deg, 0, 8192 * sizeof(int), stream);  // deg + cursor
  deg_count<<<E_EDGES / 256, 256, 0, stream>>>(colp, deg);
  dinv_kernel<<<N_NODES / 256, 256, 0, stream>>>(deg, dinv);
  scan_kernel<<<1, 1024, 0, stream>>>(deg, offs);
  fill_csr<<<E_EDGES / 256, 256, 0, stream>>>(rowp, colp, offs, cursor, csrc);

  // GCN branch
  gemm2<32, false, false, false, false><<<dim3(128, 2), 256, 0, stream>>>(
      x, W1, nullptr, nullptr, bufA, 128, 128);
  gcn_agg<<<N_NODES, 128, 0, stream>>>(bufA, dinv, offs, csrc, b1, bufB);
  gemm2<32, false, false, false, false><<<dim3(128, 2), 256, 0, stream>>>(
      bufB, W2, nullptr, nullptr, bufA, 128, 128);
  gcn_agg<<<N_NODES, 128, 0, stream>>>(bufA, dinv, offs, csrc, b2, bufB);
  // x_gnn = h2@W3 + b3 -> bufA
  gemm2<16, false, true, false, false><<<dim3(256, 1), 256, 0, stream>>>(
      bufB, W3, b3, nullptr, bufA, 64, C_OUT);

  // transformer branch
  gemm2<32, true, true, false, false><<<dim3(128, 6), 256, 0, stream>>>(
      x, ipw, ipb, nullptr, qkv, 128, 384);
  attn_kernel<<<dim3(64, NHEADS), 256, 0, stream>>>(qkv, obuf);
  gemm2<32, true, true, false, false><<<dim3(128, 2), 256, 0, stream>>>(
      obuf, opw, opb, nullptr, bufB, 128, 128);
  // out = relu(x_tf @ proj_w + proj_b + x_gnn)
  gemm2<16, false, true, true, true><<<dim3(256, 1), 256, 0, stream>>>(
      bufB, pw, pb, bufA, out, 64, C_OUT);
}

// Round 3
// 337.182 us; speedup vs baseline: 1.3171x; 1.1332x over previous
//
#include <hip/hip_runtime.h>
#include <math.h>

#define N_NODES 4096
#define F_DIM   128
#define E_EDGES 131072
#define NHEADS  8
#define HD      16
#define C_OUT   64

// ---------------- graph prep ----------------
__global__ void deg_count(const int* __restrict__ col, int* __restrict__ deg) {
  int e = blockIdx.x * blockDim.x + threadIdx.x;
  if (e < E_EDGES) atomicAdd(&deg[col[e]], 1);
}

// exclusive prefix sum of deg[4096] -> offs[4097], plus dinv; 1024 thr x 4
__global__ void scan_kernel(const int* __restrict__ deg, int* __restrict__ offs,
                            float* __restrict__ dinv) {
  __shared__ int part[1024];
  int t = threadIdx.x;
  int v0 = deg[t*4+0], v1 = deg[t*4+1], v2 = deg[t*4+2], v3 = deg[t*4+3];
  dinv[t*4+0] = rsqrtf((float)(v0 + 1));
  dinv[t*4+1] = rsqrtf((float)(v1 + 1));
  dinv[t*4+2] = rsqrtf((float)(v2 + 1));
  dinv[t*4+3] = rsqrtf((float)(v3 + 1));
  int s = v0 + v1 + v2 + v3;
  part[t] = s;
  __syncthreads();
  for (int off = 1; off < 1024; off <<= 1) {
    int x = (t >= off) ? part[t - off] : 0;
    __syncthreads();
    part[t] += x;
    __syncthreads();
  }
  int excl = part[t] - s;
  offs[t*4+0] = excl; excl += v0;
  offs[t*4+1] = excl; excl += v1;
  offs[t*4+2] = excl; excl += v2;
  offs[t*4+3] = excl; excl += v3;
  if (t == 1023) offs[4096] = excl;
}

__global__ void fill_csr(const int* __restrict__ row, const int* __restrict__ col,
                         const int* __restrict__ offs, int* __restrict__ cursor,
                         int* __restrict__ src) {
  int e = blockIdx.x * blockDim.x + threadIdx.x;
  if (e < E_EDGES) {
    int c = col[e];
    int p = atomicAdd(&cursor[c], 1);
    src[offs[c] + p] = row[e];
  }
}

// 8 nodes/block, 32 lanes x float4 per node.
__global__ __launch_bounds__(256) void gcn_agg(const float* __restrict__ t,
                                               const float* __restrict__ dinv,
                                               const int* __restrict__ offs,
                                               const int* __restrict__ src,
                                               const float* __restrict__ bias,
                                               float* __restrict__ out) {
  const int node = blockIdx.x * 8 + (threadIdx.x >> 5);
  const int lane = threadIdx.x & 31;
  const float dc = dinv[node];
  float4 a0 = *(const float4*)&t[node * F_DIM + lane * 4];
  a0.x *= dc; a0.y *= dc; a0.z *= dc; a0.w *= dc;
  float4 a1 = make_float4(0.f, 0.f, 0.f, 0.f);
  int e = offs[node], end = offs[node + 1];
  for (; e + 2 <= end; e += 2) {
    int r0 = src[e], r1 = src[e + 1];
    float w0 = dinv[r0], w1 = dinv[r1];
    const float4 v0 = *(const float4*)&t[r0 * F_DIM + lane * 4];
    const float4 v1 = *(const float4*)&t[r1 * F_DIM + lane * 4];
    a0.x = fmaf(w0, v0.x, a0.x); a0.y = fmaf(w0, v0.y, a0.y);
    a0.z = fmaf(w0, v0.z, a0.z); a0.w = fmaf(w0, v0.w, a0.w);
    a1.x = fmaf(w1, v1.x, a1.x); a1.y = fmaf(w1, v1.y, a1.y);
    a1.z = fmaf(w1, v1.z, a1.z); a1.w = fmaf(w1, v1.w, a1.w);
  }
  if (e < end) {
    int r0 = src[e];
    float w0 = dinv[r0];
    const float4 v0 = *(const float4*)&t[r0 * F_DIM + lane * 4];
    a0.x = fmaf(w0, v0.x, a0.x); a0.y = fmaf(w0, v0.y, a0.y);
    a0.z = fmaf(w0, v0.z, a0.z); a0.w = fmaf(w0, v0.w, a0.w);
  }
  a0.x += a1.x; a0.y += a1.y; a0.z += a1.z; a0.w += a1.w;
  const float4 bb = *(const float4*)&bias[lane * 4];
  float4 r;
  r.x = fmaxf(fmaf(a0.x, dc, bb.x), 0.f);
  r.y = fmaxf(fmaf(a0.y, dc, bb.y), 0.f);
  r.z = fmaxf(fmaf(a0.z, dc, bb.z), 0.f);
  r.w = fmaxf(fmaf(a0.w, dc, bb.w), 0.f);
  *(float4*)&out[node * F_DIM + lane * 4] = r;
}

// ---------------- GEMM: TM x 64 tile, BK=32, 256 threads ----------------
// NT=false: B is [K x ldb] row-major; NT=true: B is [Ntot x K] row-major.
// DUAL: C = epi(A@B + A2@B2 + bias + bias2)
template<int TM, bool NT, bool BIAS, bool RELU, bool DUAL>
__global__ __launch_bounds__(256) void gemm2(const float* __restrict__ A,
                                             const float* __restrict__ B,
                                             const float* __restrict__ bias,
                                             const float* __restrict__ A2,
                                             const float* __restrict__ B2,
                                             const float* __restrict__ bias2,
                                             float* __restrict__ C,
                                             int ldb, int ldc) {
  constexpr int K = 128, BK = 32, TN = 64;
  constexpr int RM = TM * TN / 1024;
  constexpr int LDA = 36;
  constexpr int LDB = TN + 4;
  __shared__ float As[BK * LDA];
  __shared__ float Bs[BK * LDB];
  const int tid = threadIdx.x;
  const int tx = tid & 15;
  const int ty = tid >> 4;
  const int row0 = blockIdx.x * TM;
  const int jg0  = blockIdx.y * TN;

  float acc[RM][4];
  #pragma unroll
  for (int r = 0; r < RM; ++r) { acc[r][0]=0.f; acc[r][1]=0.f; acc[r][2]=0.f; acc[r][3]=0.f; }

  for (int pass = 0; pass < (DUAL ? 2 : 1); ++pass) {
    const float* Ap = (DUAL && pass) ? A2 : A;
    const float* Bp = (DUAL && pass) ? B2 : B;
    for (int kc = 0; kc < K; kc += BK) {
      __syncthreads();
      {
        constexpr int NL = TM * BK / 4;
        for (int idx = tid; idx < NL; idx += 256) {
          int m  = idx >> 3;
          int k4 = idx & 7;
          const float4 g = *(const float4*)&Ap[(row0 + m) * K + kc + k4 * 4];
          As[(k4*4+0)*LDA + m] = g.x;
          As[(k4*4+1)*LDA + m] = g.y;
          As[(k4*4+2)*LDA + m] = g.z;
          As[(k4*4+3)*LDA + m] = g.w;
        }
      }
      if constexpr (NT) {
        constexpr int NL = TN * 8;
        for (int idx = tid; idx < NL; idx += 256) {
          int n  = idx >> 3;
          int k4 = idx & 7;
          const float4 g = *(const float4*)&Bp[(jg0 + n) * K + kc + k4 * 4];
          Bs[(k4*4+0)*LDB + n] = g.x;
          Bs[(k4*4+1)*LDB + n] = g.y;
          Bs[(k4*4+2)*LDB + n] = g.z;
          Bs[(k4*4+3)*LDB + n] = g.w;
        }
      } else {
        constexpr int NL = BK * TN / 4;
        for (int idx = tid; idx < NL; idx += 256) {
          int k  = idx >> 4;
          int n4 = idx & 15;
          *(float4*)&Bs[k * LDB + n4 * 4] =
              *(const float4*)&Bp[(kc + k) * ldb + jg0 + n4 * 4];
        }
      }
      __syncthreads();
      #pragma unroll
      for (int k = 0; k < BK; ++k) {
        const float4 bv = *(const float4*)&Bs[k * LDB + tx * 4];
        #pragma unroll
        for (int r = 0; r < RM; ++r) {
          const float a = As[k * LDA + ty * RM + r];
          acc[r][0] = fmaf(a, bv.x, acc[r][0]);
          acc[r][1] = fmaf(a, bv.y, acc[r][1]);
          acc[r][2] = fmaf(a, bv.z, acc[r][2]);
          acc[r][3] = fmaf(a, bv.w, acc[r][3]);
        }
      }
    }
  }

  #pragma unroll
  for (int r = 0; r < RM; ++r) {
    const int gr = row0 + ty * RM + r;
    const int gc = jg0 + tx * 4;
    float4 v = make_float4(acc[r][0], acc[r][1], acc[r][2], acc[r][3]);
    if constexpr (BIAS) {
      const float4 bb = *(const float4*)&bias[gc];
      v.x += bb.x; v.y += bb.y; v.z += bb.z; v.w += bb.w;
    }
    if constexpr (DUAL) {
      const float4 bb = *(const float4*)&bias2[gc];
      v.x += bb.x; v.y += bb.y; v.z += bb.z; v.w += bb.w;
    }
    if constexpr (RELU) {
      v.x = fmaxf(v.x, 0.f); v.y = fmaxf(v.y, 0.f);
      v.z = fmaxf(v.z, 0.f); v.w = fmaxf(v.w, 0.f);
    }
    *(float4*)&C[gr * ldc + gc] = v;
  }
}

// ---------------- flash attention v3: 4 rows/thread, 1/16 keys ----------------
// LDS traffic per thread per key-pair(K,V): 128 B feeding 4 rows = 2 FLOP/B.
__global__ __launch_bounds__(256, 2) void attn_kernel(const float* __restrict__ qkv,
                                                      float* __restrict__ o) {
  constexpr int TQ = 64, TK = 512;
  __shared__ float smem[2 * TK * HD + 2 * TQ * 16];  // Ks|Vs (reused for merge) + m|l
  float* Ks = smem;
  float* Vs = smem + TK * HD;
  float* mbuf = smem + 2 * TK * HD;
  float* lbuf = mbuf + TQ * 16;
  const int h   = blockIdx.y;
  const int rg  = threadIdx.x >> 4;     // 16 groups x 4 rows
  const int sub = threadIdx.x & 15;     // key stride 16
  const int row0 = blockIdx.x * TQ + rg * 4;

  float4 q[4][4];
  #pragma unroll
  for (int r = 0; r < 4; ++r) {
    const float4* qp = (const float4*)&qkv[(row0 + r) * 384 + h * HD];
    #pragma unroll
    for (int c = 0; c < 4; ++c) {
      float4 v = qp[c];
      v.x *= 0.25f; v.y *= 0.25f; v.z *= 0.25f; v.w *= 0.25f;
      q[r][c] = v;
    }
  }
  float m[4] = {-INFINITY, -INFINITY, -INFINITY, -INFINITY};
  float l[4] = {0.f, 0.f, 0.f, 0.f};
  float4 oa[4][4];
  #pragma unroll
  for (int r = 0; r < 4; ++r)
    #pragma unroll
    for (int c = 0; c < 4; ++c) oa[r][c] = make_float4(0.f, 0.f, 0.f, 0.f);

  for (int kt = 0; kt < N_NODES; kt += TK) {
    __syncthreads();
    for (int fi = threadIdx.x; fi < TK * HD / 4; fi += 256) {
      int r = fi >> 2, c4 = fi & 3;
      ((float4*)Ks)[fi] = *(const float4*)&qkv[(kt + r) * 384 + 128 + h * HD + c4 * 4];
      ((float4*)Vs)[fi] = *(const float4*)&qkv[(kt + r) * 384 + 256 + h * HD + c4 * 4];
    }
    __syncthreads();

    for (int j0 = 0; j0 < TK; j0 += 64) {        // thread keys: j0 + kk*16 + sub
      float s[4][4];                              // [row][kk]
      #pragma unroll
      for (int kk = 0; kk < 4; ++kk) {
        const float4* kp = (const float4*)&Ks[(j0 + kk * 16 + sub) * HD];
        const float4 k0 = kp[0], k1 = kp[1], k2 = kp[2], k3 = kp[3];
        #pragma unroll
        for (int r = 0; r < 4; ++r) {
          float p0 = fmaf(q[r][0].x,k0.x, fmaf(q[r][0].y,k0.y, fmaf(q[r][0].z,k0.z, q[r][0].w*k0.w)));
          float p1 = fmaf(q[r][1].x,k1.x, fmaf(q[r][1].y,k1.y, fmaf(q[r][1].z,k1.z, q[r][1].w*k1.w)));
          float p2 = fmaf(q[r][2].x,k2.x, fmaf(q[r][2].y,k2.y, fmaf(q[r][2].z,k2.z, q[r][2].w*k2.w)));
          float p3 = fmaf(q[r][3].x,k3.x, fmaf(q[r][3].y,k3.y, fmaf(q[r][3].z,k3.z, q[r][3].w*k3.w)));
          s[r][kk] = (p0 + p1) + (p2 + p3);
        }
      }
      #pragma unroll
      for (int r = 0; r < 4; ++r) {
        float bm = fmaxf(fmaxf(s[r][0], s[r][1]), fmaxf(s[r][2], s[r][3]));
        float mn = fmaxf(m[r], bm);
        float cor = __expf(m[r] - mn);
        m[r] = mn;
        s[r][0] = __expf(s[r][0] - mn);
        s[r][1] = __expf(s[r][1] - mn);
        s[r][2] = __expf(s[r][2] - mn);
        s[r][3] = __expf(s[r][3] - mn);
        l[r] = fmaf(l[r], cor, (s[r][0] + s[r][1]) + (s[r][2] + s[r][3]));
        #pragma unroll
        for (int c = 0; c < 4; ++c) {
          oa[r][c].x *= cor; oa[r][c].y *= cor; oa[r][c].z *= cor; oa[r][c].w *= cor;
        }
      }
      #pragma unroll
      for (int kk = 0; kk < 4; ++kk) {
        const float4* vp = (const float4*)&Vs[(j0 + kk * 16 + sub) * HD];
        const float4 v0 = vp[0], v1 = vp[1], v2 = vp[2], v3 = vp[3];
        #pragma unroll
        for (int r = 0; r < 4; ++r) {
          const float p = s[r][kk];
          oa[r][0].x = fmaf(p, v0.x, oa[r][0].x); oa[r][0].y = fmaf(p, v0.y, oa[r][0].y);
          oa[r][0].z = fmaf(p, v0.z, oa[r][0].z); oa[r][0].w = fmaf(p, v0.w, oa[r][0].w);
          oa[r][1].x = fmaf(p, v1.x, oa[r][1].x); oa[r][1].y = fmaf(p, v1.y, oa[r][1].y);
          oa[r][1].z = fmaf(p, v1.z, oa[r][1].z); oa[r][1].w = fmaf(p, v1.w, oa[r][1].w);
          oa[r][2].x = fmaf(p, v2.x, oa[r][2].x); oa[r][2].y = fmaf(p, v2.y, oa[r][2].y);
          oa[r][2].z = fmaf(p, v2.z, oa[r][2].z); oa[r][2].w = fmaf(p, v2.w, oa[r][2].w);
          oa[r][3].x = fmaf(p, v3.x, oa[r][3].x); oa[r][3].y = fmaf(p, v3.y, oa[r][3].y);
          oa[r][3].z = fmaf(p, v3.z, oa[r][3].z); oa[r][3].w = fmaf(p, v3.w, oa[r][3].w);
        }
      }
    }
  }
  __syncthreads();
  // write 16 partials per row (overwrites Ks/Vs region)
  #pragma unroll
  for (int r = 0; r < 4; ++r) {
    const int rl = rg * 4 + r;
    mbuf[rl * 16 + sub] = m[r];
    lbuf[rl * 16 + sub] = l[r];
    #pragma unroll
    for (int c = 0; c < 4; ++c)
      *(float4*)&smem[(rl * 16 + sub) * HD + c * 4] = oa[r][c];
  }
  __syncthreads();
  // merge: thread = (row, dgroup)
  const int row = threadIdx.x >> 2;
  const int g   = threadIdx.x & 3;
  float M = -INFINITY;
  #pragma unroll
  for (int t16 = 0; t16 < 16; ++t16) M = fmaxf(M, mbuf[row * 16 + t16]);
  float L = 0.f;
  float4 acc = make_float4(0.f, 0.f, 0.f, 0.f);
  #pragma unroll
  for (int t16 = 0; t16 < 16; ++t16) {
    const float w = __expf(mbuf[row * 16 + t16] - M);
    L = fmaf(lbuf[row * 16 + t16], w, L);
    const float4 ov = *(const float4*)&smem[(row * 16 + t16) * HD + g * 4];
    acc.x = fmaf(ov.x, w, acc.x); acc.y = fmaf(ov.y, w, acc.y);
    acc.z = fmaf(ov.z, w, acc.z); acc.w = fmaf(ov.w, w, acc.w);
  }
  const float invL = 1.f / L;
  acc.x *= invL; acc.y *= invL; acc.z *= invL; acc.w *= invL;
  *(float4*)&o[(blockIdx.x * TQ + row) * F_DIM + h * HD + g * 4] = acc;
}

// ---------------- launcher ----------------
extern "C" void kernel_launch(void* const* d_in, const int* in_sizes, int n_in,
                              void* d_out, int out_size, void* d_ws, size_t ws_size,
                              hipStream_t stream) {
  const float* x   = (const float*)d_in[0];
  const int*   ei  = (const int*)  d_in[1];
  const float* W1  = (const float*)d_in[2];
  const float* b1  = (const float*)d_in[3];
  const float* W2  = (const float*)d_in[4];
  const float* b2  = (const float*)d_in[5];
  const float* W3  = (const float*)d_in[6];
  const float* b3  = (const float*)d_in[7];
  const float* ipw = (const float*)d_in[8];
  const float* ipb = (const float*)d_in[9];
  const float* opw = (const float*)d_in[10];
  const float* opb = (const float*)d_in[11];
  const float* pw  = (const float*)d_in[12];
  const float* pb  = (const float*)d_in[13];
  float* out = (float*)d_out;

  int*   deg    = (int*)d_ws;            // 4096
  int*   cursor = deg + 4096;            // 4096
  int*   offs   = cursor + 4096;         // 4100 (4097 used)
  int*   csrc   = offs + 4100;           // 131072
  float* dinv   = (float*)(csrc + E_EDGES);        // 4096
  float* bufA   = dinv + 4096;           // 524288 (t1/t2, then x_tf)
  float* bufB   = bufA + 524288;         // 524288 (h1/h2)
  float* qkv    = bufB + 524288;         // 1572864
  float* obuf   = qkv + 1572864;         // 524288

  const int* rowp = ei;
  const int* colp = ei + E_EDGES;

  hipMemsetAsync(deg, 0, 8192 * sizeof(int), stream);  // deg + cursor
  deg_count<<<E_EDGES / 256, 256, 0, stream>>>(colp, deg);
  scan_kernel<<<1, 1024, 0, stream>>>(deg, offs, dinv);
  fill_csr<<<E_EDGES / 256, 256, 0, stream>>>(rowp, colp, offs, cursor, csrc);

  // GCN branch
  gemm2<32, false, false, false, false><<<dim3(128, 2), 256, 0, stream>>>(
      x, W1, nullptr, nullptr, nullptr, nullptr, bufA, 128, 128);
  gcn_agg<<<N_NODES / 8, 256, 0, stream>>>(bufA, dinv, offs, csrc, b1, bufB);
  gemm2<32, false, false, false, false><<<dim3(128, 2), 256, 0, stream>>>(
      bufB, W2, nullptr, nullptr, nullptr, nullptr, bufA, 128, 128);
  gcn_agg<<<N_NODES / 8, 256, 0, stream>>>(bufA, dinv, offs, csrc, b2, bufB);
  // bufB = h2 (kept for final dual GEMM)

  // transformer branch
  gemm2<32, true, true, false, false><<<dim3(128, 6), 256, 0, stream>>>(
      x, ipw, ipb, nullptr, nullptr, nullptr, qkv, 128, 384);
  attn_kernel<<<dim3(64, NHEADS), 256, 0, stream>>>(qkv, obuf);
  gemm2<32, true, true, false, false><<<dim3(128, 2), 256, 0, stream>>>(
      obuf, opw, opb, nullptr, nullptr, nullptr, bufA, 128, 128);  // bufA = x_tf

  // out = relu(h2@W3 + b3 + x_tf@pw + pb)
  gemm2<16, false, true, true, true><<<dim3(256, 1), 256, 0, stream>>>(
      bufB, W3, b3, bufA, pw, pb, out, 64, C_OUT);
}

// Round 4
// 329.580 us; speedup vs baseline: 1.3475x; 1.0231x over previous
//
#include <hip/hip_runtime.h>
#include <math.h>

#define N_NODES 4096
#define F_DIM   128
#define E_EDGES 131072
#define NHEADS  8
#define HD      16
#define C_OUT   64

// ---------------- graph prep ----------------
__global__ void deg_count(const int* __restrict__ col, int* __restrict__ deg) {
  int e = blockIdx.x * blockDim.x + threadIdx.x;
  if (e < E_EDGES) atomicAdd(&deg[col[e]], 1);
}

// exclusive prefix sum of deg[4096] -> offs[4097], plus dinv; 1024 thr x 4
__global__ void scan_kernel(const int* __restrict__ deg, int* __restrict__ offs,
                            float* __restrict__ dinv) {
  __shared__ int part[1024];
  int t = threadIdx.x;
  int v0 = deg[t*4+0], v1 = deg[t*4+1], v2 = deg[t*4+2], v3 = deg[t*4+3];
  dinv[t*4+0] = rsqrtf((float)(v0 + 1));
  dinv[t*4+1] = rsqrtf((float)(v1 + 1));
  dinv[t*4+2] = rsqrtf((float)(v2 + 1));
  dinv[t*4+3] = rsqrtf((float)(v3 + 1));
  int s = v0 + v1 + v2 + v3;
  part[t] = s;
  __syncthreads();
  for (int off = 1; off < 1024; off <<= 1) {
    int x = (t >= off) ? part[t - off] : 0;
    __syncthreads();
    part[t] += x;
    __syncthreads();
  }
  int excl = part[t] - s;
  offs[t*4+0] = excl; excl += v0;
  offs[t*4+1] = excl; excl += v1;
  offs[t*4+2] = excl; excl += v2;
  offs[t*4+3] = excl; excl += v3;
  if (t == 1023) offs[4096] = excl;
}

__global__ void fill_csr(const int* __restrict__ row, const int* __restrict__ col,
                         const int* __restrict__ offs, int* __restrict__ cursor,
                         int* __restrict__ src) {
  int e = blockIdx.x * blockDim.x + threadIdx.x;
  if (e < E_EDGES) {
    int c = col[e];
    int p = atomicAdd(&cursor[c], 1);
    src[offs[c] + p] = row[e];
  }
}

// 8 nodes/block, 32 lanes x float4 per node.
__global__ __launch_bounds__(256) void gcn_agg(const float* __restrict__ t,
                                               const float* __restrict__ dinv,
                                               const int* __restrict__ offs,
                                               const int* __restrict__ src,
                                               const float* __restrict__ bias,
                                               float* __restrict__ out) {
  const int node = blockIdx.x * 8 + (threadIdx.x >> 5);
  const int lane = threadIdx.x & 31;
  const float dc = dinv[node];
  float4 a0 = *(const float4*)&t[node * F_DIM + lane * 4];
  a0.x *= dc; a0.y *= dc; a0.z *= dc; a0.w *= dc;
  float4 a1 = make_float4(0.f, 0.f, 0.f, 0.f);
  int e = offs[node], end = offs[node + 1];
  for (; e + 2 <= end; e += 2) {
    int r0 = src[e], r1 = src[e + 1];
    float w0 = dinv[r0], w1 = dinv[r1];
    const float4 v0 = *(const float4*)&t[r0 * F_DIM + lane * 4];
    const float4 v1 = *(const float4*)&t[r1 * F_DIM + lane * 4];
    a0.x = fmaf(w0, v0.x, a0.x); a0.y = fmaf(w0, v0.y, a0.y);
    a0.z = fmaf(w0, v0.z, a0.z); a0.w = fmaf(w0, v0.w, a0.w);
    a1.x = fmaf(w1, v1.x, a1.x); a1.y = fmaf(w1, v1.y, a1.y);
    a1.z = fmaf(w1, v1.z, a1.z); a1.w = fmaf(w1, v1.w, a1.w);
  }
  if (e < end) {
    int r0 = src[e];
    float w0 = dinv[r0];
    const float4 v0 = *(const float4*)&t[r0 * F_DIM + lane * 4];
    a0.x = fmaf(w0, v0.x, a0.x); a0.y = fmaf(w0, v0.y, a0.y);
    a0.z = fmaf(w0, v0.z, a0.z); a0.w = fmaf(w0, v0.w, a0.w);
  }
  a0.x += a1.x; a0.y += a1.y; a0.z += a1.z; a0.w += a1.w;
  const float4 bb = *(const float4*)&bias[lane * 4];
  float4 r;
  r.x = fmaxf(fmaf(a0.x, dc, bb.x), 0.f);
  r.y = fmaxf(fmaf(a0.y, dc, bb.y), 0.f);
  r.z = fmaxf(fmaf(a0.z, dc, bb.z), 0.f);
  r.w = fmaxf(fmaf(a0.w, dc, bb.w), 0.f);
  *(float4*)&out[node * F_DIM + lane * 4] = r;
}

// ---------------- GEMM: TM x 64 tile, BK=32, 256 threads ----------------
// NT=false: B is [K x ldb] row-major; NT=true: B is [Ntot x K] row-major.
// DUAL: C = epi(A@B + A2@B2 + bias + bias2)
template<int TM, bool NT, bool BIAS, bool RELU, bool DUAL>
__global__ __launch_bounds__(256) void gemm2(const float* __restrict__ A,
                                             const float* __restrict__ B,
                                             const float* __restrict__ bias,
                                             const float* __restrict__ A2,
                                             const float* __restrict__ B2,
                                             const float* __restrict__ bias2,
                                             float* __restrict__ C,
                                             int ldb, int ldc) {
  constexpr int K = 128, BK = 32, TN = 64;
  constexpr int RM = TM * TN / 1024;
  constexpr int LDA = 36;
  constexpr int LDB = TN + 4;
  __shared__ float As[BK * LDA];
  __shared__ float Bs[BK * LDB];
  const int tid = threadIdx.x;
  const int tx = tid & 15;
  const int ty = tid >> 4;
  const int row0 = blockIdx.x * TM;
  const int jg0  = blockIdx.y * TN;

  float acc[RM][4];
  #pragma unroll
  for (int r = 0; r < RM; ++r) { acc[r][0]=0.f; acc[r][1]=0.f; acc[r][2]=0.f; acc[r][3]=0.f; }

  for (int pass = 0; pass < (DUAL ? 2 : 1); ++pass) {
    const float* Ap = (DUAL && pass) ? A2 : A;
    const float* Bp = (DUAL && pass) ? B2 : B;
    for (int kc = 0; kc < K; kc += BK) {
      __syncthreads();
      {
        constexpr int NL = TM * BK / 4;
        for (int idx = tid; idx < NL; idx += 256) {
          int m  = idx >> 3;
          int k4 = idx & 7;
          const float4 g = *(const float4*)&Ap[(row0 + m) * K + kc + k4 * 4];
          As[(k4*4+0)*LDA + m] = g.x;
          As[(k4*4+1)*LDA + m] = g.y;
          As[(k4*4+2)*LDA + m] = g.z;
          As[(k4*4+3)*LDA + m] = g.w;
        }
      }
      if constexpr (NT) {
        constexpr int NL = TN * 8;
        for (int idx = tid; idx < NL; idx += 256) {
          int n  = idx >> 3;
          int k4 = idx & 7;
          const float4 g = *(const float4*)&Bp[(jg0 + n) * K + kc + k4 * 4];
          Bs[(k4*4+0)*LDB + n] = g.x;
          Bs[(k4*4+1)*LDB + n] = g.y;
          Bs[(k4*4+2)*LDB + n] = g.z;
          Bs[(k4*4+3)*LDB + n] = g.w;
        }
      } else {
        constexpr int NL = BK * TN / 4;
        for (int idx = tid; idx < NL; idx += 256) {
          int k  = idx >> 4;
          int n4 = idx & 15;
          *(float4*)&Bs[k * LDB + n4 * 4] =
              *(const float4*)&Bp[(kc + k) * ldb + jg0 + n4 * 4];
        }
      }
      __syncthreads();
      #pragma unroll
      for (int k = 0; k < BK; ++k) {
        const float4 bv = *(const float4*)&Bs[k * LDB + tx * 4];
        #pragma unroll
        for (int r = 0; r < RM; ++r) {
          const float a = As[k * LDA + ty * RM + r];
          acc[r][0] = fmaf(a, bv.x, acc[r][0]);
          acc[r][1] = fmaf(a, bv.y, acc[r][1]);
          acc[r][2] = fmaf(a, bv.z, acc[r][2]);
          acc[r][3] = fmaf(a, bv.w, acc[r][3]);
        }
      }
    }
  }

  #pragma unroll
  for (int r = 0; r < RM; ++r) {
    const int gr = row0 + ty * RM + r;
    const int gc = jg0 + tx * 4;
    float4 v = make_float4(acc[r][0], acc[r][1], acc[r][2], acc[r][3]);
    if constexpr (BIAS) {
      const float4 bb = *(const float4*)&bias[gc];
      v.x += bb.x; v.y += bb.y; v.z += bb.z; v.w += bb.w;
    }
    if constexpr (DUAL) {
      const float4 bb = *(const float4*)&bias2[gc];
      v.x += bb.x; v.y += bb.y; v.z += bb.z; v.w += bb.w;
    }
    if constexpr (RELU) {
      v.x = fmaxf(v.x, 0.f); v.y = fmaxf(v.y, 0.f);
      v.z = fmaxf(v.z, 0.f); v.w = fmaxf(v.w, 0.f);
    }
    *(float4*)&C[gr * ldc + gc] = v;
  }
}

// ---------------- flash attention v4 ----------------
// 4 rows/thread, 1/16 keys; K/V rows padded to 20 floats (80 B) in LDS so the
// 16 sub-lanes' b128 reads spread over all 32 banks (2-way = free, m136).
// TK=256 to fit padding in same 73728 B. Rescale per 8 keys (s[4][8]).
__global__ __launch_bounds__(256, 2) void attn_kernel(const float* __restrict__ qkv,
                                                      float* __restrict__ o) {
  constexpr int TQ = 64, TK = 256, LDK = 20;
  // region 0..16383: Ks(5120) | Vs(5120) during main loop; o-partials (1024x16)
  // during merge. 16384..18431: mbuf | lbuf.
  __shared__ float smem[18432];
  float* Ks = smem;
  float* Vs = smem + TK * LDK;
  float* mbuf = smem + 16384;
  float* lbuf = mbuf + TQ * 16;
  const int h   = blockIdx.y;
  const int rg  = threadIdx.x >> 4;     // 16 groups x 4 rows
  const int sub = threadIdx.x & 15;     // key stride 16
  const int row0 = blockIdx.x * TQ + rg * 4;

  float4 q[4][4];
  #pragma unroll
  for (int r = 0; r < 4; ++r) {
    const float4* qp = (const float4*)&qkv[(row0 + r) * 384 + h * HD];
    #pragma unroll
    for (int c = 0; c < 4; ++c) {
      float4 v = qp[c];
      v.x *= 0.25f; v.y *= 0.25f; v.z *= 0.25f; v.w *= 0.25f;
      q[r][c] = v;
    }
  }
  float m[4] = {-INFINITY, -INFINITY, -INFINITY, -INFINITY};
  float l[4] = {0.f, 0.f, 0.f, 0.f};
  float4 oa[4][4];
  #pragma unroll
  for (int r = 0; r < 4; ++r)
    #pragma unroll
    for (int c = 0; c < 4; ++c) oa[r][c] = make_float4(0.f, 0.f, 0.f, 0.f);

  for (int kt = 0; kt < N_NODES; kt += TK) {
    __syncthreads();
    for (int fi = threadIdx.x; fi < TK * 4; fi += 256) {
      int r = fi >> 2, c4 = fi & 3;
      *(float4*)&Ks[r * LDK + c4 * 4] =
          *(const float4*)&qkv[(kt + r) * 384 + 128 + h * HD + c4 * 4];
      *(float4*)&Vs[r * LDK + c4 * 4] =
          *(const float4*)&qkv[(kt + r) * 384 + 256 + h * HD + c4 * 4];
    }
    __syncthreads();

    for (int j0 = 0; j0 < TK; j0 += 128) {       // thread keys: j0 + kk*16 + sub
      float s[4][8];
      #pragma unroll
      for (int kk = 0; kk < 8; ++kk) {
        const float4* kp = (const float4*)&Ks[(j0 + kk * 16 + sub) * LDK];
        const float4 k0 = kp[0], k1 = kp[1], k2 = kp[2], k3 = kp[3];
        #pragma unroll
        for (int r = 0; r < 4; ++r) {
          float p0 = fmaf(q[r][0].x,k0.x, fmaf(q[r][0].y,k0.y, fmaf(q[r][0].z,k0.z, q[r][0].w*k0.w)));
          float p1 = fmaf(q[r][1].x,k1.x, fmaf(q[r][1].y,k1.y, fmaf(q[r][1].z,k1.z, q[r][1].w*k1.w)));
          float p2 = fmaf(q[r][2].x,k2.x, fmaf(q[r][2].y,k2.y, fmaf(q[r][2].z,k2.z, q[r][2].w*k2.w)));
          float p3 = fmaf(q[r][3].x,k3.x, fmaf(q[r][3].y,k3.y, fmaf(q[r][3].z,k3.z, q[r][3].w*k3.w)));
          s[r][kk] = (p0 + p1) + (p2 + p3);
        }
      }
      #pragma unroll
      for (int r = 0; r < 4; ++r) {
        float bm = fmaxf(fmaxf(fmaxf(s[r][0], s[r][1]), fmaxf(s[r][2], s[r][3])),
                         fmaxf(fmaxf(s[r][4], s[r][5]), fmaxf(s[r][6], s[r][7])));
        float mn = fmaxf(m[r], bm);
        float cor = __expf(m[r] - mn);
        m[r] = mn;
        #pragma unroll
        for (int kk = 0; kk < 8; ++kk) s[r][kk] = __expf(s[r][kk] - mn);
        float ps = ((s[r][0]+s[r][1]) + (s[r][2]+s[r][3])) +
                   ((s[r][4]+s[r][5]) + (s[r][6]+s[r][7]));
        l[r] = fmaf(l[r], cor, ps);
        #pragma unroll
        for (int c = 0; c < 4; ++c) {
          oa[r][c].x *= cor; oa[r][c].y *= cor; oa[r][c].z *= cor; oa[r][c].w *= cor;
        }
      }
      #pragma unroll
      for (int kk = 0; kk < 8; ++kk) {
        const float4* vp = (const float4*)&Vs[(j0 + kk * 16 + sub) * LDK];
        const float4 v0 = vp[0], v1 = vp[1], v2 = vp[2], v3 = vp[3];
        #pragma unroll
        for (int r = 0; r < 4; ++r) {
          const float p = s[r][kk];
          oa[r][0].x = fmaf(p, v0.x, oa[r][0].x); oa[r][0].y = fmaf(p, v0.y, oa[r][0].y);
          oa[r][0].z = fmaf(p, v0.z, oa[r][0].z); oa[r][0].w = fmaf(p, v0.w, oa[r][0].w);
          oa[r][1].x = fmaf(p, v1.x, oa[r][1].x); oa[r][1].y = fmaf(p, v1.y, oa[r][1].y);
          oa[r][1].z = fmaf(p, v1.z, oa[r][1].z); oa[r][1].w = fmaf(p, v1.w, oa[r][1].w);
          oa[r][2].x = fmaf(p, v2.x, oa[r][2].x); oa[r][2].y = fmaf(p, v2.y, oa[r][2].y);
          oa[r][2].z = fmaf(p, v2.z, oa[r][2].z); oa[r][2].w = fmaf(p, v2.w, oa[r][2].w);
          oa[r][3].x = fmaf(p, v3.x, oa[r][3].x); oa[r][3].y = fmaf(p, v3.y, oa[r][3].y);
          oa[r][3].z = fmaf(p, v3.z, oa[r][3].z); oa[r][3].w = fmaf(p, v3.w, oa[r][3].w);
        }
      }
    }
  }
  __syncthreads();
  // write 16 partials per row (overwrites Ks/Vs region)
  #pragma unroll
  for (int r = 0; r < 4; ++r) {
    const int rl = rg * 4 + r;
    mbuf[rl * 16 + sub] = m[r];
    lbuf[rl * 16 + sub] = l[r];
    #pragma unroll
    for (int c = 0; c < 4; ++c)
      *(float4*)&smem[(rl * 16 + sub) * HD + c * 4] = oa[r][c];
  }
  __syncthreads();
  // merge: thread = (row, dgroup)
  const int row = threadIdx.x >> 2;
  const int g   = threadIdx.x & 3;
  float M = -INFINITY;
  #pragma unroll
  for (int t16 = 0; t16 < 16; ++t16) M = fmaxf(M, mbuf[row * 16 + t16]);
  float L = 0.f;
  float4 acc = make_float4(0.f, 0.f, 0.f, 0.f);
  #pragma unroll
  for (int t16 = 0; t16 < 16; ++t16) {
    const float w = __expf(mbuf[row * 16 + t16] - M);
    L = fmaf(lbuf[row * 16 + t16], w, L);
    const float4 ov = *(const float4*)&smem[(row * 16 + t16) * HD + g * 4];
    acc.x = fmaf(ov.x, w, acc.x); acc.y = fmaf(ov.y, w, acc.y);
    acc.z = fmaf(ov.z, w, acc.z); acc.w = fmaf(ov.w, w, acc.w);
  }
  const float invL = 1.f / L;
  acc.x *= invL; acc.y *= invL; acc.z *= invL; acc.w *= invL;
  *(float4*)&o[(blockIdx.x * TQ + row) * F_DIM + h * HD + g * 4] = acc;
}

// ---------------- launcher ----------------
extern "C" void kernel_launch(void* const* d_in, const int* in_sizes, int n_in,
                              void* d_out, int out_size, void* d_ws, size_t ws_size,
                              hipStream_t stream) {
  const float* x   = (const float*)d_in[0];
  const int*   ei  = (const int*)  d_in[1];
  const float* W1  = (const float*)d_in[2];
  const float* b1  = (const float*)d_in[3];
  const float* W2  = (const float*)d_in[4];
  const float* b2  = (const float*)d_in[5];
  const float* W3  = (const float*)d_in[6];
  const float* b3  = (const float*)d_in[7];
  const float* ipw = (const float*)d_in[8];
  const float* ipb = (const float*)d_in[9];
  const float* opw = (const float*)d_in[10];
  const float* opb = (const float*)d_in[11];
  const float* pw  = (const float*)d_in[12];
  const float* pb  = (const float*)d_in[13];
  float* out = (float*)d_out;

  int*   deg    = (int*)d_ws;            // 4096
  int*   cursor = deg + 4096;            // 4096
  int*   offs   = cursor + 4096;         // 4100 (4097 used)
  int*   csrc   = offs + 4100;           // 131072
  float* dinv   = (float*)(csrc + E_EDGES);        // 4096
  float* bufA   = dinv + 4096;           // 524288 (t1/t2, then x_tf)
  float* bufB   = bufA + 524288;         // 524288 (h1/h2)
  float* qkv    = bufB + 524288;         // 1572864
  float* obuf   = qkv + 1572864;         // 524288

  const int* rowp = ei;
  const int* colp = ei + E_EDGES;

  hipMemsetAsync(deg, 0, 8192 * sizeof(int), stream);  // deg + cursor
  deg_count<<<E_EDGES / 256, 256, 0, stream>>>(colp, deg);
  scan_kernel<<<1, 1024, 0, stream>>>(deg, offs, dinv);
  fill_csr<<<E_EDGES / 256, 256, 0, stream>>>(rowp, colp, offs, cursor, csrc);

  // GCN branch
  gemm2<32, false, false, false, false><<<dim3(128, 2), 256, 0, stream>>>(
      x, W1, nullptr, nullptr, nullptr, nullptr, bufA, 128, 128);
  gcn_agg<<<N_NODES / 8, 256, 0, stream>>>(bufA, dinv, offs, csrc, b1, bufB);
  gemm2<32, false, false, false, false><<<dim3(128, 2), 256, 0, stream>>>(
      bufB, W2, nullptr, nullptr, nullptr, nullptr, bufA, 128, 128);
  gcn_agg<<<N_NODES / 8, 256, 0, stream>>>(bufA, dinv, offs, csrc, b2, bufB);
  // bufB = h2 (kept for final dual GEMM)

  // transformer branch
  gemm2<32, true, true, false, false><<<dim3(128, 6), 256, 0, stream>>>(
      x, ipw, ipb, nullptr, nullptr, nullptr, qkv, 128, 384);
  attn_kernel<<<dim3(64, NHEADS), 256, 0, stream>>>(qkv, obuf);
  gemm2<32, true, true, false, false><<<dim3(128, 2), 256, 0, stream>>>(
      obuf, opw, opb, nullptr, nullptr, nullptr, bufA, 128, 128);  // bufA = x_tf

  // out = relu(h2@W3 + b3 + x_tf@pw + pb)
  gemm2<16, false, true, true, true><<<dim3(256, 1), 256, 0, stream>>>(
      bufB, W3, b3, bufA, pw, pb, out, 64, C_OUT);
}